// Round 8
// baseline (2561.899 us; speedup 1.0000x reference)
//
#include <hip/hip_runtime.h>
#include <stdint.h>

typedef __attribute__((ext_vector_type(8))) short bf16x8;
typedef __attribute__((ext_vector_type(4))) float f32x4;

#define NE 320000
#define NNODES 20000
// LDS: H 65536 | W0 32768 | W1 32768 | bias 3584 | colsum 512
#define SMEM_BYTES 135168

#define VMCNT(N) asm volatile("s_waitcnt vmcnt(" #N ")" ::: "memory")
#define LGKM0() asm volatile("s_waitcnt lgkmcnt(0)" ::: "memory")
#define BAR() __builtin_amdgcn_s_barrier()
#define SCHED0() __builtin_amdgcn_sched_barrier(0)

__device__ __forceinline__ unsigned short f2bf(float f) {
  union { float f; unsigned int u; } v; v.f = f;
  unsigned int u = v.u;
  u += 0x7fffu + ((u >> 16) & 1u);  // RNE
  return (unsigned short)(u >> 16);
}

__device__ __forceinline__ void gload_lds16(const void* g, void* l) {
  __builtin_amdgcn_global_load_lds((const __attribute__((address_space(1))) void*)g,
                                   (__attribute__((address_space(3))) void*)l, 16, 0, 0);
}

// ---- weight packing: W[K][N] fp32 -> A-fragment order (W^T frags) ----
// frag f = s*NG + g; element j of lane ln = W[s*32 + (ln>>4)*8 + j][g*16 + (ln&15)]
struct PackArgs {
  const float* src[8];
  unsigned short* dst[8];
  int K[8];
  int N[8];
};

__global__ void pack_weights(PackArgs a) {
  int m = blockIdx.y;
  int K = a.K[m], N = a.N[m];
  int NG = N >> 4;
  int total = (K >> 5) * NG * 64;
  int idx = blockIdx.x * 256 + threadIdx.x;
  if (idx >= total) return;
  int ln = idx & 63, f = idx >> 6;
  int g = f % NG, s = f / NG;
  const float* src = a.src[m];
  int krow = s * 32 + ((ln >> 4) & 3) * 8;
  int col = g * 16 + (ln & 15);
  bf16x8 p;
#pragma unroll
  for (int j = 0; j < 8; ++j) p[j] = (short)f2bf(src[(size_t)(krow + j) * N + col]);
  *(bf16x8*)(a.dst[m] + (size_t)idx * 8) = p;
}

// RNE bf16x8 from 8 fp32 (R1-proven numerics)
__device__ __forceinline__ bf16x8 cvt8(const f32x4& a, const f32x4& b) {
  bf16x8 r;
#pragma unroll
  for (int j = 0; j < 4; ++j) {
    r[j] = (short)f2bf(a[j]);
    r[4 + j] = (short)f2bf(b[j]);
  }
  return r;
}

// write relu(accT + bias) into H[m][n] bf16, stride 512B, XOR-swizzled; zero acc
template <bool REL>
__device__ __forceinline__ void store_H(char* Hb, const float* biasL, int boff,
                                        f32x4 (&acc)[2][4], int wm, int wn, int t, int cl) {
#pragma unroll
  for (int mg = 0; mg < 2; ++mg) {
    int m = wm * 32 + mg * 16 + cl;
    int sw = (m & 7) << 4;
    int mb = m * 512;
#pragma unroll
    for (int g = 0; g < 4; ++g) {
      int n = wn * 64 + g * 16 + t * 4;
      f32x4 bv = *(const f32x4*)(biasL + boff + n);
      f32x4 v = acc[mg][g] + bv;
      if (REL) {
#pragma unroll
        for (int j = 0; j < 4; ++j) v[j] = fmaxf(v[j], 0.0f);
      }
      unsigned lo = (unsigned)f2bf(v[0]) | ((unsigned)f2bf(v[1]) << 16);
      unsigned hi = (unsigned)f2bf(v[2]) | ((unsigned)f2bf(v[3]) << 16);
      *(unsigned*)(Hb + ((mb + n * 2) ^ sw)) = lo;
      *(unsigned*)(Hb + ((mb + n * 2 + 4) ^ sw)) = hi;
      f32x4 z = {0.f, 0.f, 0.f, 0.f};
      acc[mg][g] = z;
    }
  }
}

// MODE 0: edge MLP (K1=512, X = [g|n_s|n_r|edges], agg atomics, e_sum)
// MODE 1: node MLP (K1=384, X = [g|nodes|agg], n_sum)
template <int MODE>
__global__ __launch_bounds__(1024, 4) void fused_mlp(
    const float* __restrict__ gvec, const float* __restrict__ nodes,
    const float* __restrict__ third, const int* __restrict__ senders,
    const int* __restrict__ receivers,
    const unsigned short* __restrict__ pw1, const unsigned short* __restrict__ pw2,
    const unsigned short* __restrict__ pw3, const unsigned short* __restrict__ pw4,
    const float* __restrict__ b1, const float* __restrict__ b2,
    const float* __restrict__ b3, const float* __restrict__ b4,
    float* __restrict__ outp, float* __restrict__ aggp, float* __restrict__ colsum) {
  constexpr int K1 = (MODE == 0) ? 512 : 384;
  constexpr int C1 = K1 / 64;          // L1 chunks (8 / 6)
  constexpr int CT = C1 + 4 + 4 + 2;   // total 32KB chunks
  constexpr int NROWS = (MODE == 0) ? NE : NNODES;

  extern __shared__ char smem[];
  char* Hb = smem;                     // 65536 : H [128][256] bf16 (or [128][128] f32)
  char* Wb0 = smem + 65536;            // 32768
  char* Wb1 = smem + 98304;            // 32768
  float* biasL = (float*)(smem + 131072);  // 896 floats
  float* csL = (float*)(smem + 134656);    // 128 floats

  const int tid = threadIdx.x;
  const int lane = tid & 63;
  const int wv = tid >> 6;
  const int wm = wv >> 2, wn = wv & 3;
  const int t = lane >> 4, cl = lane & 15;
  const int row0 = blockIdx.x * 128;

  // ---- prologue: bias + colsum LDS ----
  if (tid < 896) {
    float bvv;
    if (tid < 256) bvv = b1[tid];
    else if (tid < 512) bvv = b2[tid - 256];
    else if (tid < 768) bvv = b3[tid - 512];
    else bvv = b4[tid - 768];
    biasL[tid] = bvv;
  }
  if (tid < 128) csL[tid] = 0.0f;

  // per-lane source row pointers (2 m-groups)
  const float* rp[2][4];
#pragma unroll
  for (int mg = 0; mg < 2; ++mg) {
    int i = row0 + wm * 32 + mg * 16 + cl;
    rp[mg][0] = gvec;
    if (MODE == 0) {
      rp[mg][1] = nodes + (size_t)senders[i] * 128;
      rp[mg][2] = nodes + (size_t)receivers[i] * 128;
      rp[mg][3] = third + (size_t)i * 128;
    } else {
      int iv = i < NROWS ? i : (NROWS - 1);
      rp[mg][1] = nodes + (size_t)iv * 128;
      rp[mg][2] = third + (size_t)iv * 128;
      rp[mg][3] = gvec;
    }
  }

  // W chunk source (uniform scalar)
  auto wsrc = [&](int gc) -> const unsigned short* {
    if (gc < C1) return pw1 + (size_t)gc * 16384;
    gc -= C1;
    if (gc < 4) return pw2 + (size_t)gc * 16384;
    gc -= 4;
    if (gc < 4) return pw3 + (size_t)gc * 16384;
    return pw4 + (size_t)(gc - 4) * 16384;
  };
  auto stageW = [&](int gc) {
    if (gc >= CT) return;
    const char* p = (const char*)wsrc(gc);
    char* d = (gc & 1) ? Wb1 : Wb0;
    gload_lds16(p + tid * 16, d + tid * 16);
    gload_lds16(p + tid * 16 + 16384, d + tid * 16 + 16384);
  };

  f32x4 xf[2][2][2];
#define LOAD_X(c)                                                                   \
  {                                                                                 \
    _Pragma("unroll") for (int mg = 0; mg < 2; ++mg) {                              \
      _Pragma("unroll") for (int s2 = 0; s2 < 2; ++s2) {                            \
        int s = (c) * 2 + s2;                                                       \
        const float* sp = rp[mg][s >> 2] + ((s * 32) & 127) + t * 8;                \
        xf[mg][s2][0] = *(const f32x4*)sp;                                          \
        xf[mg][s2][1] = *(const f32x4*)(sp + 4);                                    \
      }                                                                             \
    }                                                                               \
  }

  f32x4 acc[2][4];
  {
    f32x4 z = {0.f, 0.f, 0.f, 0.f};
#pragma unroll
    for (int mg = 0; mg < 2; ++mg)
#pragma unroll
      for (int g = 0; g < 4; ++g) acc[mg][g] = z;
  }

  // prologue issues: W0, X0, W1
  stageW(0);
  LOAD_X(0);
  stageW(1);

  // ---------------- layer 1 ----------------
#pragma unroll
  for (int c = 0; c < C1; ++c) {
    VMCNT(10);   // retire stageW(c) (FIFO: 10 = stageW(c+1)[2] + LOAD_X in flight[8])
    SCHED0();
    BAR();
    bf16x8 xb[2][2];
#pragma unroll
    for (int mg = 0; mg < 2; ++mg)
#pragma unroll
      for (int s2 = 0; s2 < 2; ++s2) xb[mg][s2] = cvt8(xf[mg][s2][0], xf[mg][s2][1]);
    const char* wb = (c & 1) ? Wb1 : Wb0;
#pragma unroll
    for (int s2 = 0; s2 < 2; ++s2)
#pragma unroll
      for (int g = 0; g < 4; ++g) {
        bf16x8 af = *(const bf16x8*)(wb + ((s2 * 16 + wn * 4 + g) << 10) + lane * 16);
#pragma unroll
        for (int mg = 0; mg < 2; ++mg)
          acc[mg][g] = __builtin_amdgcn_mfma_f32_16x16x32_bf16(af, xb[mg][s2], acc[mg][g], 0, 0, 0);
      }
    // RACE FIX: drain our ds_reads of Wb before the handoff barrier — a wave may
    // otherwise arrive at s_barrier with reads pending while another wave's
    // stageW(c+2) DMA overwrites the same buffer (R6/R7 corruption).
    LGKM0();
    SCHED0();
    BAR();
    stageW(c + 2);
    if (c + 1 < C1) LOAD_X(c + 1);
  }
  store_H<true>(Hb, biasL, 0, acc, wm, wn, t, cl);
  LGKM0();  // H writes drained before next loop's barrier

  // ---------------- layers 2,3 ----------------
#pragma unroll
  for (int L = 0; L < 2; ++L) {
    const int base = C1 + L * 4;
#pragma unroll
    for (int c = 0; c < 4; ++c) {
      VMCNT(2);  // retire stageW(base+c); leave stageW(base+c+1) in flight
      SCHED0();
      BAR();
      const char* wb = ((base + c) & 1) ? Wb1 : Wb0;
#pragma unroll
      for (int s2 = 0; s2 < 2; ++s2) {
        bf16x8 bfm[2];
#pragma unroll
        for (int mg = 0; mg < 2; ++mg) {
          int m = wm * 32 + mg * 16 + cl;
          int off = (m * 512 + (c * 2 + s2) * 64 + t * 16) ^ ((m & 7) << 4);
          bfm[mg] = *(const bf16x8*)(Hb + off);
        }
#pragma unroll
        for (int g = 0; g < 4; ++g) {
          bf16x8 af = *(const bf16x8*)(wb + ((s2 * 16 + wn * 4 + g) << 10) + lane * 16);
#pragma unroll
          for (int mg = 0; mg < 2; ++mg)
            acc[mg][g] = __builtin_amdgcn_mfma_f32_16x16x32_bf16(af, bfm[mg], acc[mg][g], 0, 0, 0);
        }
      }
      LGKM0();  // drain Hb/Wb reads before handoff (race fix)
      SCHED0();
      BAR();
      stageW(base + c + 2);
    }
    store_H<true>(Hb, biasL, 256 + L * 256, acc, wm, wn, t, cl);
    LGKM0();
  }

  // ---------------- layer 4 (N=128) ----------------
#pragma unroll
  for (int c = 0; c < 2; ++c) {
    if (c == 0) { VMCNT(2); } else { VMCNT(0); }
    SCHED0();
    BAR();
    const char* wb = ((C1 + 8 + c) & 1) ? Wb1 : Wb0;
#pragma unroll
    for (int s2 = 0; s2 < 4; ++s2) {
      bf16x8 bfm[2];
#pragma unroll
      for (int mg = 0; mg < 2; ++mg) {
        int m = wm * 32 + mg * 16 + cl;
        int off = (m * 512 + (c * 4 + s2) * 64 + t * 16) ^ ((m & 7) << 4);
        bfm[mg] = *(const bf16x8*)(Hb + off);
      }
#pragma unroll
      for (int g = 0; g < 2; ++g) {
        bf16x8 af = *(const bf16x8*)(wb + ((s2 * 8 + wn * 2 + g) << 10) + lane * 16);
#pragma unroll
        for (int mg = 0; mg < 2; ++mg)
          acc[mg][g] = __builtin_amdgcn_mfma_f32_16x16x32_bf16(af, bfm[mg], acc[mg][g], 0, 0, 0);
      }
    }
    LGKM0();  // drain Hb reads before epilogue overwrites Hb (race fix)
    SCHED0();
    BAR();
  }

  // ---------------- epilogue ----------------
  // write acc + b4 as f32 into Hb [128][128], stride 512B, swizzled
#pragma unroll
  for (int mg = 0; mg < 2; ++mg) {
    int m = wm * 32 + mg * 16 + cl;
    int sw = (m & 7) << 4;
    int mb = m * 512;
#pragma unroll
    for (int g = 0; g < 2; ++g) {
      int n = wn * 32 + g * 16 + t * 4;
      f32x4 bv = *(const f32x4*)(biasL + 768 + n);
      f32x4 v = acc[mg][g] + bv;
      float2 p0 = {v[0], v[1]}, p1 = {v[2], v[3]};
      *(float2*)(Hb + ((mb + n * 4) ^ sw)) = p0;
      *(float2*)(Hb + ((mb + n * 4 + 8) ^ sw)) = p1;
    }
  }
  LGKM0();
  SCHED0();
  BAR();

  {
    int r = tid >> 3, cw = tid & 7;
    int e = row0 + r;
    bool valid = (MODE == 0) ? true : (e < NROWS);
    f32x4 o[4];
#pragma unroll
    for (int i = 0; i < 4; ++i)
      o[i] = *(const f32x4*)(Hb + ((r * 512 + cw * 64 + i * 16) ^ ((r & 7) << 4)));
    if (valid) {
      float* op = outp + (size_t)e * 128 + cw * 16;
#pragma unroll
      for (int i = 0; i < 4; ++i) *(f32x4*)(op + i * 4) = o[i];
      if (MODE == 0) {
        float* ap = aggp + (size_t)receivers[e] * 128 + cw * 16;
#pragma unroll
        for (int i = 0; i < 4; ++i)
#pragma unroll
          for (int j = 0; j < 4; ++j) atomicAdd(ap + i * 4 + j, o[i][j]);
      }
    }
    // column sums: reduce 8 rows within wave, then LDS, then global
#pragma unroll
    for (int i = 0; i < 4; ++i)
#pragma unroll
      for (int j = 0; j < 4; ++j) {
        float v = valid ? o[i][j] : 0.0f;
        v += __shfl_xor(v, 8);
        v += __shfl_xor(v, 16);
        v += __shfl_xor(v, 32);
        if (lane < 8) atomicAdd(&csL[cw * 16 + i * 4 + j], v);
      }
  }
  LGKM0();
  SCHED0();
  BAR();
  if (tid < 128) atomicAdd(colsum + tid, csL[tid]);
#undef LOAD_X
}

// tiny fp32 global MLP: x = [g | n_sum | e_sum]
__global__ void global_mlp(const float* __restrict__ g, const float* __restrict__ nsum,
                           const float* __restrict__ esum, const float* __restrict__ w1,
                           const float* __restrict__ bb1, const float* __restrict__ w2,
                           const float* __restrict__ bb2, const float* __restrict__ w3,
                           const float* __restrict__ bb3, const float* __restrict__ w4,
                           const float* __restrict__ bb4, float* __restrict__ outg) {
  __shared__ float x[384], h1[256], h2[256], h3[256];
  int tq = threadIdx.x;
  if (tq < 128) x[tq] = g[tq];
  else if (tq < 256) x[tq] = nsum[tq - 128];
  else x[tq] = esum[tq - 256];
  __syncthreads();
  if (tq < 256) {
    float a = bb1[tq];
    for (int k = 0; k < 384; ++k) a = fmaf(x[k], w1[k * 256 + tq], a);
    h1[tq] = fmaxf(a, 0.f);
  }
  __syncthreads();
  if (tq < 256) {
    float a = bb2[tq];
    for (int k = 0; k < 256; ++k) a = fmaf(h1[k], w2[k * 256 + tq], a);
    h2[tq] = fmaxf(a, 0.f);
  }
  __syncthreads();
  if (tq < 256) {
    float a = bb3[tq];
    for (int k = 0; k < 256; ++k) a = fmaf(h2[k], w3[k * 256 + tq], a);
    h3[tq] = fmaxf(a, 0.f);
  }
  __syncthreads();
  if (tq < 128) {
    float a = bb4[tq];
    for (int k = 0; k < 256; ++k) a = fmaf(h3[k], w4[k * 128 + tq], a);
    outg[tq] = a;
  }
}

extern "C" void kernel_launch(void* const* d_in, const int* in_sizes, int n_in, void* d_out,
                              int out_size, void* d_ws, size_t ws_size, hipStream_t stream) {
  const float* g = (const float*)d_in[0];
  const float* nodes = (const float*)d_in[1];
  const float* edges = (const float*)d_in[2];
  const int* senders = (const int*)d_in[3];
  const int* receivers = (const int*)d_in[4];
  const float* ew[4] = {(const float*)d_in[5], (const float*)d_in[7], (const float*)d_in[9],
                        (const float*)d_in[11]};
  const float* eb[4] = {(const float*)d_in[6], (const float*)d_in[8], (const float*)d_in[10],
                        (const float*)d_in[12]};
  const float* nw[4] = {(const float*)d_in[13], (const float*)d_in[15], (const float*)d_in[17],
                        (const float*)d_in[19]};
  const float* nb[4] = {(const float*)d_in[14], (const float*)d_in[16], (const float*)d_in[18],
                        (const float*)d_in[20]};
  const float* gw[4] = {(const float*)d_in[21], (const float*)d_in[23], (const float*)d_in[25],
                        (const float*)d_in[27]};
  const float* gb[4] = {(const float*)d_in[22], (const float*)d_in[24], (const float*)d_in[26],
                        (const float*)d_in[28]};

  float* out = (float*)d_out;
  float* e_new = out;
  float* n_new = out + (size_t)NE * 128;
  float* g_new = n_new + (size_t)NNODES * 128;

  // workspace layout
  char* ws = (char*)d_ws;
  unsigned short* pe1 = (unsigned short*)ws;           // 512x256
  unsigned short* pe2 = pe1 + 512 * 256;               // 256x256
  unsigned short* pe3 = pe2 + 256 * 256;               // 256x256
  unsigned short* pe4 = pe3 + 256 * 256;               // 256x128
  unsigned short* pn1 = pe4 + 256 * 128;               // 384x256
  unsigned short* pn2 = pn1 + 384 * 256;               // 256x256
  unsigned short* pn3 = pn2 + 256 * 256;               // 256x256
  unsigned short* pn4 = pn3 + 256 * 256;               // 256x128
  float* agg = (float*)(ws + 1114112);                 // 20000x128 fp32
  float* esum = agg + (size_t)NNODES * 128;            // 128
  float* nsum = esum + 128;                            // 128

  hipMemsetAsync(agg, 0, (size_t)NNODES * 128 * 4 + 1024, stream);

  PackArgs pa;
  const float* srcs[8] = {ew[0], ew[1], ew[2], ew[3], nw[0], nw[1], nw[2], nw[3]};
  unsigned short* dsts[8] = {pe1, pe2, pe3, pe4, pn1, pn2, pn3, pn4};
  int Ks[8] = {512, 256, 256, 256, 384, 256, 256, 256};
  int Ns[8] = {256, 256, 256, 128, 256, 256, 256, 128};
  for (int i = 0; i < 8; ++i) {
    pa.src[i] = srcs[i];
    pa.dst[i] = dsts[i];
    pa.K[i] = Ks[i];
    pa.N[i] = Ns[i];
  }
  pack_weights<<<dim3(64, 8), 256, 0, stream>>>(pa);

  hipFuncSetAttribute((const void*)&fused_mlp<0>, hipFuncAttributeMaxDynamicSharedMemorySize,
                      SMEM_BYTES);
  hipFuncSetAttribute((const void*)&fused_mlp<1>, hipFuncAttributeMaxDynamicSharedMemorySize,
                      SMEM_BYTES);

  fused_mlp<0><<<NE / 128, 1024, SMEM_BYTES, stream>>>(
      g, nodes, edges, senders, receivers, pe1, pe2, pe3, pe4, eb[0], eb[1], eb[2], eb[3], e_new,
      agg, esum);
  fused_mlp<1><<<(NNODES + 127) / 128, 1024, SMEM_BYTES, stream>>>(
      g, nodes, agg, senders, receivers, pn1, pn2, pn3, pn4, nb[0], nb[1], nb[2], nb[3], n_new,
      nullptr, nsum);
  global_mlp<<<1, 384, 0, stream>>>(g, nsum, esum, gw[0], gb[0], gw[1], gb[1], gw[2], gb[2], gw[3],
                                    gb[3], g_new);
}